// Round 5
// baseline (628.783 us; speedup 1.0000x reference)
//
#include <hip/hip_runtime.h>
#include <math.h>

#define NN    50000
#define NE    800000
#define NET   850000     // edges + self loops
#define NETP  850048
#define NG    64
#define KIN   500
#define NEG   0.2f

typedef unsigned short ushort_t;
typedef __attribute__((ext_vector_type(8))) short bf8_t;       // 8 bf16 in 4 VGPRs
typedef __attribute__((ext_vector_type(8))) unsigned short us8_t;
typedef __attribute__((ext_vector_type(4))) float f4_t;

__device__ __forceinline__ float bf2f(ushort_t u) {
    unsigned v = ((unsigned)u) << 16;
    return __builtin_bit_cast(float, v);
}
__device__ __forceinline__ ushort_t f2bf(float f) {
    unsigned b = __builtin_bit_cast(unsigned, f);
    unsigned r = (b + 0x7FFFu + ((b >> 16) & 1u)) >> 16;   // RNE
    return (ushort_t)r;
}

#define GLOAD_LDS(g, l)                                                        \
    __builtin_amdgcn_global_load_lds(                                          \
        (const __attribute__((address_space(1))) unsigned int*)(g),            \
        (__attribute__((address_space(3))) unsigned int*)(l), 16, 0, 0)

// ---------------- prep: degree count + weight transpose/cast (merged) ----------
__global__ void k_prep(const int* __restrict__ ei, int* __restrict__ deg,
                       const float* __restrict__ W1, ushort_t* __restrict__ Wt1,
                       const float* __restrict__ W2, ushort_t* __restrict__ Wt2)
{
    int b = blockIdx.x;
    if (b < 3321) {                                  // degree histogram
        int e = b * 256 + threadIdx.x;
        if (e < NET) {
            int dst = (e < NE) ? ei[NE + e] : (e - NE);
            atomicAdd(&deg[dst], 1);
        }
    } else if (b < 3321 + 512) {                     // Wt1 [256][512] (K-pad 500->512)
        int idx = (b - 3321) * 256 + threadIdx.x;
        int n = idx >> 9, k = idx & 511;
        Wt1[idx] = f2bf(k < KIN ? W1[(size_t)k * 256 + n] : 0.f);
    } else {                                         // Wt2 [64][256]
        int idx = (b - 3833) * 256 + threadIdx.x;
        int n = idx >> 8, k = idx & 255;
        Wt2[idx] = f2bf(W2[(size_t)k * 64 + n]);
    }
}

// ---------------- CSR scan + fill ----------------
__global__ void k_scan_part(const int* __restrict__ deg, int* __restrict__ part) {
    __shared__ int s[256];
    int t = threadIdx.x;
    int i = blockIdx.x * 256 + t;
    s[t] = (i < NN) ? deg[i] : 0;
    __syncthreads();
    for (int off = 128; off > 0; off >>= 1) {
        if (t < off) s[t] += s[t + off];
        __syncthreads();
    }
    if (t == 0) part[blockIdx.x] = s[0];
}

__global__ void k_scan_top(int* __restrict__ part, int nb) {
    __shared__ int s[256];
    int t = threadIdx.x;
    int v = (t < nb) ? part[t] : 0;
    s[t] = v;
    __syncthreads();
    for (int off = 1; off < 256; off <<= 1) {
        int a = (t >= off) ? s[t - off] : 0;
        __syncthreads();
        s[t] += a;
        __syncthreads();
    }
    if (t < nb) part[t] = s[t] - v;   // exclusive
}

__global__ void k_scan_apply(const int* __restrict__ deg, const int* __restrict__ part,
                             int* __restrict__ rowptr) {
    __shared__ int s[256];
    int t = threadIdx.x;
    int i = blockIdx.x * 256 + t;
    int v = (i < NN) ? deg[i] : 0;
    s[t] = v;
    __syncthreads();
    for (int off = 1; off < 256; off <<= 1) {
        int a = (t >= off) ? s[t - off] : 0;
        __syncthreads();
        s[t] += a;
        __syncthreads();
    }
    if (i < NN) rowptr[i] = part[blockIdx.x] + s[t] - v;
    if (i == 0) rowptr[NN] = NET;
}

__global__ void k_fill(const int* __restrict__ ei, const int* __restrict__ rowptr,
                       int* __restrict__ cursor, int* __restrict__ csr) {
    int e = blockIdx.x * 256 + threadIdx.x;
    if (e >= NET) return;
    int src, dst;
    if (e < NE) { src = ei[e]; dst = ei[NE + e]; }
    else        { src = dst = e - NE; }
    int pos = atomicAdd(&cursor[dst], 1);
    csr[rowptr[dst] + pos] = src;
}

// ---------------- bf16 MFMA GEMM, sliced-transposed H output + fused logits ----
// AF32: A is fp32, converted to bf16 during LDS staging (kills the cast pass).
// hT layout: [slice][node][32feat] bf16, slice = global_col >> 5.
template <int K, int KSRC, int LDA, int BM, int BN, int WM, int HEADS, bool AF32>
__global__ __launch_bounds__(256) void k_mfma(
    const void* __restrict__ Ap, const ushort_t* __restrict__ Wt,
    const float* __restrict__ a_s, const float* __restrict__ a_d,
    ushort_t* __restrict__ hT, float* __restrict__ als, float* __restrict__ ald)
{
    __shared__ __align__(16) ushort_t lA[BM * 32];
    __shared__ __align__(16) ushort_t lB[BN * 32];
    const int t    = threadIdx.x;
    const int row0 = blockIdx.y * BM;
    const int n0   = blockIdx.x * BN;
    const int ww   = t >> 6, lane = t & 63;
    const int wm   = ww % WM, wn = ww / WM;
    const int lrow = lane & 15, lq = lane >> 4;   // quad

    f4_t acc[4][4] = {};

    for (int k0 = 0; k0 < K; k0 += 32) {
        if constexpr (AF32) {
            const float* Af = (const float*)Ap;
#pragma unroll
            for (int i = 0; i < BM * 32 / 1024; i++) {   // 4-elt chunks, fp32->bf16
                int c = i * 256 + t;
                int row = c >> 3, kq = c & 7;
                int rg = row0 + row; if (rg >= NN) rg = 0;   // clamp pad rows
                int kg = k0 + kq * 4;
                float4 v = make_float4(0.f, 0.f, 0.f, 0.f);
                if (kg < KSRC) v = *(const float4*)&Af[(size_t)rg * LDA + kg];
                ushort4 u = make_ushort4(f2bf(v.x), f2bf(v.y), f2bf(v.z), f2bf(v.w));
                *(ushort4*)&lA[row * 32 + kq * 4] = u;
            }
        } else {
            const ushort_t* Ab = (const ushort_t*)Ap;
#pragma unroll
            for (int i = 0; i < BM / 64; i++) {
                int c = i * 256 + t;
                int row = c >> 2, kq = c & 3;
                const ushort_t* gp = Ab + (size_t)(row0 + row) * LDA + k0 + kq * 8;
                GLOAD_LDS(gp, &lA[c * 8]);
            }
        }
#pragma unroll
        for (int i = 0; i < BN / 64; i++) {       // B tile: BN cols x 32 k
            int c = i * 256 + t;
            int row = c >> 2, kq = c & 3;
            const ushort_t* gp = Wt + (size_t)(n0 + row) * K + k0 + kq * 8;
            GLOAD_LDS(gp, &lB[c * 8]);
        }
        __syncthreads();
        bf8_t af[4], bfr[4];
#pragma unroll
        for (int i = 0; i < 4; i++)
            af[i] = *(const bf8_t*)&lA[(wm * 64 + i * 16 + lrow) * 32 + lq * 8];
#pragma unroll
        for (int j = 0; j < 4; j++)
            bfr[j] = *(const bf8_t*)&lB[(wn * 64 + j * 16 + lrow) * 32 + lq * 8];
#pragma unroll
        for (int i = 0; i < 4; i++)
#pragma unroll
            for (int j = 0; j < 4; j++)
                acc[i][j] = __builtin_amdgcn_mfma_f32_16x16x32_bf16(af[i], bfr[j], acc[i][j], 0, 0, 0);
        __syncthreads();
    }

    // epilogue: wave's 64 cols = one head (64-aligned); write sliced-transposed H
    const int head  = (n0 + wn * 64) >> 6;
    const int sbase = (n0 + wn * 64) >> 5;
    float as4[4], ad4[4];
#pragma unroll
    for (int j = 0; j < 4; j++) {
        as4[j] = a_s[head * 64 + j * 16 + lrow];
        ad4[j] = a_d[head * 64 + j * 16 + lrow];
    }
#pragma unroll
    for (int i = 0; i < 4; i++) {
#pragma unroll
        for (int r = 0; r < 4; r++) {
            int row = row0 + wm * 64 + i * 16 + lq * 4 + r;
            float v0 = acc[i][0][r], v1 = acc[i][1][r], v2 = acc[i][2][r], v3 = acc[i][3][r];
            if (row < NN) {
                hT[((size_t)(sbase + 0) * NN + row) * 32 +      lrow] = f2bf(v0);
                hT[((size_t)(sbase + 0) * NN + row) * 32 + 16 + lrow] = f2bf(v1);
                hT[((size_t)(sbase + 1) * NN + row) * 32 +      lrow] = f2bf(v2);
                hT[((size_t)(sbase + 1) * NN + row) * 32 + 16 + lrow] = f2bf(v3);
            }
            float ps = v0 * as4[0] + v1 * as4[1] + v2 * as4[2] + v3 * as4[3];
            float pd = v0 * ad4[0] + v1 * ad4[1] + v2 * ad4[2] + v3 * ad4[3];
#pragma unroll
            for (int off = 1; off < 16; off <<= 1) {
                ps += __shfl_xor(ps, off);
                pd += __shfl_xor(pd, off);
            }
            if (lrow == 0 && row < NN) {
                als[(size_t)row * HEADS + head] = ps;
                ald[(size_t)row * HEADS + head] = pd;
            }
        }
    }
}

// ---- layer-1 softmax pass: exact max + exp + denom; alpha stored [head][edge] ----
// wave per dst; lane = slot*4 + head (16 edge slots x 4 heads).
__global__ __launch_bounds__(256) void k_alpha1(
    const int* __restrict__ rowptr, const int* __restrict__ csr,
    const float* __restrict__ als, const float* __restrict__ ald,
    float* __restrict__ alphaH, float* __restrict__ sden)
{
    int w = threadIdx.x >> 6, lane = threadIdx.x & 63;
    int dst = blockIdx.x * 4 + w;
    if (dst >= NN) return;
    const int slot = lane >> 2, head = lane & 3;
    const int beg = rowptr[dst], end = rowptr[dst + 1];
    const float adst = ald[dst * 4 + head];

    float m = -1e30f;
    for (int i = beg + slot; i < end; i += 16) {
        float e = als[csr[i] * 4 + head] + adst;
        e = (e > 0.f) ? e : NEG * e;
        m = fmaxf(m, e);
    }
    m = fmaxf(m, __shfl_xor(m, 4));
    m = fmaxf(m, __shfl_xor(m, 8));
    m = fmaxf(m, __shfl_xor(m, 16));
    m = fmaxf(m, __shfl_xor(m, 32));

    float s = 0.f;
    for (int i = beg + slot; i < end; i += 16) {
        float e = als[csr[i] * 4 + head] + adst;
        e = (e > 0.f) ? e : NEG * e;
        float ex = __expf(e - m);
        s += ex;
        alphaH[(size_t)head * NETP + i] = ex;
    }
    s += __shfl_xor(s, 4);
    s += __shfl_xor(s, 8);
    s += __shfl_xor(s, 16);
    s += __shfl_xor(s, 32);
    if (slot == 0) sden[dst * 4 + head] = 1.f / (s + 1e-16f);
}

// ---- layer-1 gather: sliced by feature (8 slices of 32 feats = 3.2 MB, L2-resident
// per XCD via blockIdx%8 round-robin). No exp; pure alpha-weighted FMA. ----
__global__ __launch_bounds__(256) void k_gather1(
    const int* __restrict__ rowptr, const int* __restrict__ csr,
    const ushort_t* __restrict__ h1t, const float* __restrict__ alphaH,
    const float* __restrict__ sden, const float* __restrict__ bias,
    ushort_t* __restrict__ out1b)
{
    int w = threadIdx.x >> 6, lane = threadIdx.x & 63;
    int slice = blockIdx.x & 7, dgrp = blockIdx.x >> 3;
    int dst = dgrp * 4 + w;
    if (dst >= NN) return;
    const int head  = slice >> 1;
    const int fl    = lane & 3, eslot = lane >> 2;
    const int beg = rowptr[dst], end = rowptr[dst + 1];
    const ushort_t* hsl = h1t + (size_t)slice * NN * 32;
    const float*    aH  = alphaH + (size_t)head * NETP;

    float acc[8] = {};
    for (int i = beg + eslot; i < end; i += 16) {
        int src = csr[i];
        float a = aH[i];
        us8_t x8 = *(const us8_t*)&hsl[(size_t)src * 32 + fl * 8];
#pragma unroll
        for (int j = 0; j < 8; j++)
            acc[j] += a * bf2f((ushort_t)x8[j]);
    }
#pragma unroll
    for (int j = 0; j < 8; j++) {
        acc[j] += __shfl_xor(acc[j], 4);
        acc[j] += __shfl_xor(acc[j], 8);
        acc[j] += __shfl_xor(acc[j], 16);
        acc[j] += __shfl_xor(acc[j], 32);
    }
    if (eslot == 0) {
        float rs = sden[dst * 4 + head];
        int col = slice * 32 + fl * 8;
        us8_t o8;
#pragma unroll
        for (int j = 0; j < 8; j++) {
            float o = acc[j] * rs + bias[col + j];
            o8[j] = f2bf((o > 0.f) ? o : 0.f);
        }
        *(us8_t*)&out1b[(size_t)dst * 256 + col] = o8;
    }
}

// ---- layer-2 fused softmax+gather, 2 slices of 32 feats (3.2 MB each) ----
__global__ __launch_bounds__(256) void k_agg2f(
    const int* __restrict__ rowptr, const int* __restrict__ csr,
    const ushort_t* __restrict__ h2t, const float* __restrict__ als,
    const float* __restrict__ ald, const float* __restrict__ bias,
    float* __restrict__ out2)
{
    int w = threadIdx.x >> 6, lane = threadIdx.x & 63;
    int slice = blockIdx.x & 1, dgrp = blockIdx.x >> 1;
    int dst = dgrp * 4 + w;
    if (dst >= NN) return;
    const int fl = lane & 3, eslot = lane >> 2;
    const int beg = rowptr[dst], end = rowptr[dst + 1];
    const float adst = ald[dst];
    const ushort_t* hsl = h2t + (size_t)slice * NN * 32;

    float m = -1e30f;
    for (int i = beg + eslot; i < end; i += 16) {
        float e = als[csr[i]] + adst;
        e = (e > 0.f) ? e : NEG * e;
        m = fmaxf(m, e);
    }
    m = fmaxf(m, __shfl_xor(m, 4));
    m = fmaxf(m, __shfl_xor(m, 8));
    m = fmaxf(m, __shfl_xor(m, 16));
    m = fmaxf(m, __shfl_xor(m, 32));

    float s = 0.f;
    float acc[8] = {};
    for (int i = beg + eslot; i < end; i += 16) {
        int src = csr[i];
        float e = als[src] + adst;
        e = (e > 0.f) ? e : NEG * e;
        float ex = __expf(e - m);
        s += ex;
        us8_t x8 = *(const us8_t*)&hsl[(size_t)src * 32 + fl * 8];
#pragma unroll
        for (int j = 0; j < 8; j++)
            acc[j] += ex * bf2f((ushort_t)x8[j]);
    }
    s += __shfl_xor(s, 4);
    s += __shfl_xor(s, 8);
    s += __shfl_xor(s, 16);
    s += __shfl_xor(s, 32);
#pragma unroll
    for (int j = 0; j < 8; j++) {
        acc[j] += __shfl_xor(acc[j], 4);
        acc[j] += __shfl_xor(acc[j], 8);
        acc[j] += __shfl_xor(acc[j], 16);
        acc[j] += __shfl_xor(acc[j], 32);
    }
    if (eslot == 0) {
        float rs = 1.f / (s + 1e-16f);
        int col = slice * 32 + fl * 8;
        float4 o0, o1;
        float* p0 = &o0.x; float* p1 = &o1.x;
#pragma unroll
        for (int j = 0; j < 4; j++) {
            float v = acc[j] * rs + bias[col + j];
            p0[j] = (v > 0.f) ? v : 0.f;
        }
#pragma unroll
        for (int j = 0; j < 4; j++) {
            float v = acc[4 + j] * rs + bias[col + 4 + j];
            p1[j] = (v > 0.f) ? v : 0.f;
        }
        *(float4*)&out2[(size_t)dst * 64 + col]     = o0;
        *(float4*)&out2[(size_t)dst * 64 + col + 4] = o1;
    }
}

// ---------------- fused mean-pool (sorted batch) + classifier --------
__global__ void k_pool_final(const float* __restrict__ out2, const int* __restrict__ batch,
                             const float* __restrict__ Wl, const float* __restrict__ bl,
                             float* __restrict__ out)
{
    int g = blockIdx.x;
    int lo, hi;
    { int a = 0, b = NN; while (a < b) { int mm = (a + b) >> 1; if (batch[mm] < g) a = mm + 1; else b = mm; } lo = a; }
    { int a = lo, b = NN; while (a < b) { int mm = (a + b) >> 1; if (batch[mm] < g + 1) a = mm + 1; else b = mm; } hi = a; }
    int t = threadIdx.x, c = t & 63, r = t >> 6;
    float s = 0.f;
    for (int n = lo + r; n < hi; n += 4) s += out2[(size_t)n * 64 + c];
    __shared__ float red[256];
    red[t] = s;
    __syncthreads();
    if (t < 64) {
        float p = red[t] + red[t + 64] + red[t + 128] + red[t + 192];
        int cntv = hi - lo;
        p /= (float)(cntv > 0 ? cntv : 1);
        float r0 = p * Wl[t * 2 + 0];
        float r1 = p * Wl[t * 2 + 1];
#pragma unroll
        for (int off = 32; off > 0; off >>= 1) {
            r0 += __shfl_xor(r0, off);
            r1 += __shfl_xor(r1, off);
        }
        if (t == 0) {
            out[g * 2 + 0] = r0 + bl[0];
            out[g * 2 + 1] = r1 + bl[1];
        }
    }
}

extern "C" void kernel_launch(void* const* d_in, const int* in_sizes, int n_in,
                              void* d_out, int out_size, void* d_ws, size_t ws_size,
                              hipStream_t stream)
{
    const float* x    = (const float*)d_in[0];
    const int*   ei   = (const int*)  d_in[1];
    const int*   batch= (const int*)  d_in[2];
    const float* W1   = (const float*)d_in[3];
    const float* as1  = (const float*)d_in[4];
    const float* ad1  = (const float*)d_in[5];
    const float* b1   = (const float*)d_in[6];
    const float* W2   = (const float*)d_in[7];
    const float* as2  = (const float*)d_in[8];
    const float* ad2  = (const float*)d_in[9];
    const float* b2   = (const float*)d_in[10];
    const float* Wl   = (const float*)d_in[11];
    const float* bl   = (const float*)d_in[12];
    float* out = (float*)d_out;

    // ---- workspace carve-up (int units) ----
    int* p = (int*)d_ws;
    int*   deg    = p;          p += 50048;
    int*   cursor = p;          p += 50048;
    int*   part   = p;          p += 256;
    int*   rowptr = p;          p += 50064;
    int*   csr    = p;          p += 850048;
    float* al1s   = (float*)p;  p += 200000;
    float* al1d   = (float*)p;  p += 200000;
    float* al2s   = (float*)p;  p += 50048;
    float* al2d   = (float*)p;  p += 50048;
    float* sden1  = (float*)p;  p += 200000;
    float* alphaH = (float*)p;  p += 4 * NETP;
    ushort_t* Wt1 = (ushort_t*)p; p += 65536;     // 131072 ush
    ushort_t* Wt2 = (ushort_t*)p; p += 8192;      // 16384 ush
    ushort_t* h1t = (ushort_t*)p; p += 6400000;   // 8*50000*32 ush
    ushort_t* out1b = (ushort_t*)p; p += 6422528; // 50176*256 ush
    ushort_t* h2t = (ushort_t*)p; p += 1600000;   // 2*50000*32 ush
    float* out2   = (float*)h1t;                  // alias: h1t dead after gather1

    hipMemsetAsync(deg, 0, 2 * 50048 * sizeof(int), stream);               // deg+cursor
    hipMemsetAsync(out1b + (size_t)50000 * 256, 0,
                   (size_t)176 * 256 * sizeof(ushort_t), stream);          // GEMM2 M-pad

    // prep (deg histogram + weight casts) and CSR build
    k_prep      <<<3897, 256, 0, stream>>>(ei, deg, W1, Wt1, W2, Wt2);
    k_scan_part <<<196, 256, 0, stream>>>(deg, part);
    k_scan_top  <<<1,   256, 0, stream>>>(part, 196);
    k_scan_apply<<<196, 256, 0, stream>>>(deg, part, rowptr);
    k_fill      <<<(NET + 255) / 256, 256, 0, stream>>>(ei, rowptr, cursor, csr);

    // layer 1: GEMM (fp32 A staged->bf16), sliced h1t + logits; alpha pass; gather
    k_mfma<512, KIN, KIN, 128, 128, 2, 4, true><<<dim3(2, 391), 256, 0, stream>>>(
        x, Wt1, as1, ad1, h1t, al1s, al1d);
    k_alpha1 <<<(NN + 3) / 4, 256, 0, stream>>>(rowptr, csr, al1s, al1d, alphaH, sden1);
    k_gather1<<<((NN + 3) / 4) * 8, 256, 0, stream>>>(rowptr, csr, h1t, alphaH, sden1, b1, out1b);

    // layer 2: GEMM (bf16 A via global_load_lds), sliced h2t + logits; fused agg
    k_mfma<256, 256, 256, 256, 64, 4, 1, false><<<dim3(1, 196), 256, 0, stream>>>(
        out1b, Wt2, as2, ad2, h2t, al2s, al2d);
    k_agg2f<<<((NN + 3) / 4) * 2, 256, 0, stream>>>(rowptr, csr, h2t, al2s, al2d, b2, out2);

    // fused pool + classifier
    k_pool_final<<<NG, 256, 0, stream>>>(out2, batch, Wl, bl, out);
}

// Round 6
// 551.632 us; speedup vs baseline: 1.1399x; 1.1399x over previous
//
#include <hip/hip_runtime.h>
#include <math.h>

#define NN    50000
#define NE    800000
#define NET   850000     // edges + self loops
#define NETP  850048
#define NG    64
#define KIN   500
#define NEG   0.2f

typedef unsigned short ushort_t;
typedef __attribute__((ext_vector_type(8))) short bf8_t;       // 8 bf16 in 4 VGPRs
typedef __attribute__((ext_vector_type(8))) unsigned short us8_t;
typedef __attribute__((ext_vector_type(4))) float f4_t;

__device__ __forceinline__ float bf2f(ushort_t u) {
    unsigned v = ((unsigned)u) << 16;
    return __builtin_bit_cast(float, v);
}
__device__ __forceinline__ ushort_t f2bf(float f) {
    unsigned b = __builtin_bit_cast(unsigned, f);
    unsigned r = (b + 0x7FFFu + ((b >> 16) & 1u)) >> 16;   // RNE
    return (ushort_t)r;
}

#define GLOAD_LDS(g, l)                                                        \
    __builtin_amdgcn_global_load_lds(                                          \
        (const __attribute__((address_space(1))) unsigned int*)(g),            \
        (__attribute__((address_space(3))) unsigned int*)(l), 16, 0, 0)

// ---------------- prep: degree count + weight transpose/cast (merged) ----------
__global__ void k_prep(const int* __restrict__ ei, int* __restrict__ deg,
                       const float* __restrict__ W1, ushort_t* __restrict__ Wt1,
                       const float* __restrict__ W2, ushort_t* __restrict__ Wt2)
{
    int b = blockIdx.x;
    if (b < 3321) {                                  // degree histogram
        int e = b * 256 + threadIdx.x;
        if (e < NET) {
            int dst = (e < NE) ? ei[NE + e] : (e - NE);
            atomicAdd(&deg[dst], 1);
        }
    } else if (b < 3321 + 512) {                     // Wt1 [256][512] (K-pad 500->512)
        int idx = (b - 3321) * 256 + threadIdx.x;
        int n = idx >> 9, k = idx & 511;
        Wt1[idx] = f2bf(k < KIN ? W1[(size_t)k * 256 + n] : 0.f);
    } else {                                         // Wt2 [64][256]
        int idx = (b - 3833) * 256 + threadIdx.x;
        int n = idx >> 8, k = idx & 255;
        Wt2[idx] = f2bf(W2[(size_t)k * 64 + n]);
    }
}

// ---------------- CSR scan + fill ----------------
__global__ void k_scan_part(const int* __restrict__ deg, int* __restrict__ part) {
    __shared__ int s[256];
    int t = threadIdx.x;
    int i = blockIdx.x * 256 + t;
    s[t] = (i < NN) ? deg[i] : 0;
    __syncthreads();
    for (int off = 128; off > 0; off >>= 1) {
        if (t < off) s[t] += s[t + off];
        __syncthreads();
    }
    if (t == 0) part[blockIdx.x] = s[0];
}

__global__ void k_scan_top(int* __restrict__ part, int nb) {
    __shared__ int s[256];
    int t = threadIdx.x;
    int v = (t < nb) ? part[t] : 0;
    s[t] = v;
    __syncthreads();
    for (int off = 1; off < 256; off <<= 1) {
        int a = (t >= off) ? s[t - off] : 0;
        __syncthreads();
        s[t] += a;
        __syncthreads();
    }
    if (t < nb) part[t] = s[t] - v;   // exclusive
}

__global__ void k_scan_apply(const int* __restrict__ deg, const int* __restrict__ part,
                             int* __restrict__ rowptr) {
    __shared__ int s[256];
    int t = threadIdx.x;
    int i = blockIdx.x * 256 + t;
    int v = (i < NN) ? deg[i] : 0;
    s[t] = v;
    __syncthreads();
    for (int off = 1; off < 256; off <<= 1) {
        int a = (t >= off) ? s[t - off] : 0;
        __syncthreads();
        s[t] += a;
        __syncthreads();
    }
    if (i < NN) rowptr[i] = part[blockIdx.x] + s[t] - v;
    if (i == 0) rowptr[NN] = NET;
}

__global__ void k_fill(const int* __restrict__ ei, const int* __restrict__ rowptr,
                       int* __restrict__ cursor, int* __restrict__ csr) {
    int e = blockIdx.x * 256 + threadIdx.x;
    if (e >= NET) return;
    int src, dst;
    if (e < NE) { src = ei[e]; dst = ei[NE + e]; }
    else        { src = dst = e - NE; }
    int pos = atomicAdd(&cursor[dst], 1);
    csr[rowptr[dst] + pos] = src;
}

// ---------------- bf16 MFMA GEMM, contiguous H + fused attention logits ----
// AF32: A is fp32, converted to bf16 during LDS staging (no separate cast pass).
template <int K, int KSRC, int LDA, int BM, int BN, int WM, int HEADS, bool AF32>
__global__ __launch_bounds__(256) void k_mfma(
    const void* __restrict__ Ap, const ushort_t* __restrict__ Wt,
    const float* __restrict__ a_s, const float* __restrict__ a_d,
    ushort_t* __restrict__ Hb, float* __restrict__ als, float* __restrict__ ald)
{
    __shared__ __align__(16) ushort_t lA[BM * 32];
    __shared__ __align__(16) ushort_t lB[BN * 32];
    const int FOUT = HEADS * 64;
    const int t    = threadIdx.x;
    const int row0 = blockIdx.y * BM;
    const int n0   = blockIdx.x * BN;
    const int ww   = t >> 6, lane = t & 63;
    const int wm   = ww % WM, wn = ww / WM;
    const int lrow = lane & 15, lq = lane >> 4;   // quad

    f4_t acc[4][4] = {};

    for (int k0 = 0; k0 < K; k0 += 32) {
        if constexpr (AF32) {
            const float* Af = (const float*)Ap;
#pragma unroll
            for (int i = 0; i < BM * 32 / 1024; i++) {   // 4-elt chunks, fp32->bf16
                int c = i * 256 + t;
                int row = c >> 3, kq = c & 7;
                int rg = row0 + row; if (rg >= NN) rg = 0;   // clamp pad rows
                int kg = k0 + kq * 4;
                float4 v = make_float4(0.f, 0.f, 0.f, 0.f);
                if (kg < KSRC) v = *(const float4*)&Af[(size_t)rg * LDA + kg];
                ushort4 u = make_ushort4(f2bf(v.x), f2bf(v.y), f2bf(v.z), f2bf(v.w));
                *(ushort4*)&lA[row * 32 + kq * 4] = u;
            }
        } else {
            const ushort_t* Ab = (const ushort_t*)Ap;
#pragma unroll
            for (int i = 0; i < BM / 64; i++) {
                int c = i * 256 + t;
                int row = c >> 2, kq = c & 3;
                const ushort_t* gp = Ab + (size_t)(row0 + row) * LDA + k0 + kq * 8;
                GLOAD_LDS(gp, &lA[c * 8]);
            }
        }
#pragma unroll
        for (int i = 0; i < BN / 64; i++) {       // B tile: BN cols x 32 k
            int c = i * 256 + t;
            int row = c >> 2, kq = c & 3;
            const ushort_t* gp = Wt + (size_t)(n0 + row) * K + k0 + kq * 8;
            GLOAD_LDS(gp, &lB[c * 8]);
        }
        __syncthreads();
        bf8_t af[4], bfr[4];
#pragma unroll
        for (int i = 0; i < 4; i++)
            af[i] = *(const bf8_t*)&lA[(wm * 64 + i * 16 + lrow) * 32 + lq * 8];
#pragma unroll
        for (int j = 0; j < 4; j++)
            bfr[j] = *(const bf8_t*)&lB[(wn * 64 + j * 16 + lrow) * 32 + lq * 8];
#pragma unroll
        for (int i = 0; i < 4; i++)
#pragma unroll
            for (int j = 0; j < 4; j++)
                acc[i][j] = __builtin_amdgcn_mfma_f32_16x16x32_bf16(af[i], bfr[j], acc[i][j], 0, 0, 0);
        __syncthreads();
    }

    // epilogue: wave's 64 cols = one head (64-aligned); contiguous H write + logits
    const int head = (n0 + wn * 64) >> 6;
    float as4[4], ad4[4];
#pragma unroll
    for (int j = 0; j < 4; j++) {
        as4[j] = a_s[head * 64 + j * 16 + lrow];
        ad4[j] = a_d[head * 64 + j * 16 + lrow];
    }
#pragma unroll
    for (int i = 0; i < 4; i++) {
#pragma unroll
        for (int r = 0; r < 4; r++) {
            int row = row0 + wm * 64 + i * 16 + lq * 4 + r;
            float v0 = acc[i][0][r], v1 = acc[i][1][r], v2 = acc[i][2][r], v3 = acc[i][3][r];
            if (row < NN) {
                size_t base = (size_t)row * FOUT + n0 + wn * 64 + lrow;
                Hb[base +  0] = f2bf(v0);
                Hb[base + 16] = f2bf(v1);
                Hb[base + 32] = f2bf(v2);
                Hb[base + 48] = f2bf(v3);
            }
            float ps = v0 * as4[0] + v1 * as4[1] + v2 * as4[2] + v3 * as4[3];
            float pd = v0 * ad4[0] + v1 * ad4[1] + v2 * ad4[2] + v3 * ad4[3];
#pragma unroll
            for (int off = 1; off < 16; off <<= 1) {
                ps += __shfl_xor(ps, off);
                pd += __shfl_xor(pd, off);
            }
            if (lrow == 0 && row < NN) {
                als[(size_t)row * HEADS + head] = ps;
                ald[(size_t)row * HEADS + head] = pd;
            }
        }
    }
}

// ---- softmax pass: exact per-(dst,head) max -> exp -> denom.
// alphaE stored AoS [edge][HEADS]. One wave per dst; lane = slot*HEADS + head.
template <int HEADS>
__global__ __launch_bounds__(256) void k_alpha(
    const int* __restrict__ rowptr, const int* __restrict__ csr,
    const float* __restrict__ als, const float* __restrict__ ald,
    float* __restrict__ alphaE, float* __restrict__ sden)
{
    const int SLOTS = 64 / HEADS;
    int w = threadIdx.x >> 6, lane = threadIdx.x & 63;
    int dst = blockIdx.x * 4 + w;
    if (dst >= NN) return;
    const int slot = lane / HEADS, head = lane & (HEADS - 1);
    const int beg = rowptr[dst], end = rowptr[dst + 1];
    const float adst = ald[dst * HEADS + head];

    float m = -1e30f;
    for (int i = beg + slot; i < end; i += SLOTS) {
        float e = als[csr[i] * HEADS + head] + adst;
        e = (e > 0.f) ? e : NEG * e;
        m = fmaxf(m, e);
    }
#pragma unroll
    for (int off = HEADS; off < 64; off <<= 1) m = fmaxf(m, __shfl_xor(m, off));

    float s = 0.f;
    for (int i = beg + slot; i < end; i += SLOTS) {
        float e = als[csr[i] * HEADS + head] + adst;
        e = (e > 0.f) ? e : NEG * e;
        float ex = __expf(e - m);
        s += ex;
        alphaE[(size_t)i * HEADS + head] = ex;
    }
#pragma unroll
    for (int off = HEADS; off < 64; off <<= 1) s += __shfl_xor(s, off);
    if (slot == 0) sden[dst * HEADS + head] = 1.f / (s + 1e-16f);
}

// ---- layer-1 gather: one wave per dst, all 4 heads, 2 full rows/iter, pure FMA ----
// lane: slot = lane>>5 (edge), head = (lane>>3)&3, f0 = (lane&7)*8.
__global__ __launch_bounds__(256) void k_gather1(
    const int* __restrict__ rowptr, const int* __restrict__ csr,
    const ushort_t* __restrict__ Hb, const float* __restrict__ alphaE,
    const float* __restrict__ sden, const float* __restrict__ bias,
    ushort_t* __restrict__ out1b)
{
    int w = threadIdx.x >> 6, lane = threadIdx.x & 63;
    int dst = blockIdx.x * 4 + w;
    if (dst >= NN) return;
    const int slot = lane >> 5;
    const int head = (lane >> 3) & 3;
    const int f0   = (lane & 7) * 8;
    const int beg = rowptr[dst], end = rowptr[dst + 1];

    float acc[8] = {};
    for (int i = beg + slot; i < end; i += 2) {
        int   src = csr[i];
        float a   = alphaE[(size_t)i * 4 + head];
        us8_t x8  = *(const us8_t*)&Hb[(size_t)src * 256 + head * 64 + f0];
#pragma unroll
        for (int j = 0; j < 8; j++)
            acc[j] += a * bf2f((ushort_t)x8[j]);
    }
#pragma unroll
    for (int j = 0; j < 8; j++) acc[j] += __shfl_xor(acc[j], 32);
    if (lane < 32) {
        float rs = sden[dst * 4 + head];
        us8_t o8;
#pragma unroll
        for (int j = 0; j < 8; j++) {
            float o = acc[j] * rs + bias[head * 64 + f0 + j];
            o8[j] = f2bf((o > 0.f) ? o : 0.f);
        }
        *(us8_t*)&out1b[(size_t)dst * 256 + head * 64 + f0] = o8;
    }
}

// ---- layer-2 gather: one wave per dst, 4 rows/iter, pure FMA ----
// lane: slot = lane>>4 (edge), f0 = (lane&15)*4.
__global__ __launch_bounds__(256) void k_gather2(
    const int* __restrict__ rowptr, const int* __restrict__ csr,
    const ushort_t* __restrict__ Hb, const float* __restrict__ alphaE,
    const float* __restrict__ sden, const float* __restrict__ bias,
    float* __restrict__ out2)
{
    int w = threadIdx.x >> 6, lane = threadIdx.x & 63;
    int dst = blockIdx.x * 4 + w;
    if (dst >= NN) return;
    const int slot = lane >> 4;
    const int f0   = (lane & 15) * 4;
    const int beg = rowptr[dst], end = rowptr[dst + 1];

    float acc[4] = {};
    for (int i = beg + slot; i < end; i += 4) {
        int src = csr[i];
        float a = alphaE[i];
        ushort4 xv = *(const ushort4*)&Hb[(size_t)src * 64 + f0];
        acc[0] += a * bf2f(xv.x);
        acc[1] += a * bf2f(xv.y);
        acc[2] += a * bf2f(xv.z);
        acc[3] += a * bf2f(xv.w);
    }
#pragma unroll
    for (int j = 0; j < 4; j++) {
        acc[j] += __shfl_xor(acc[j], 16);
        acc[j] += __shfl_xor(acc[j], 32);
    }
    if (lane < 16) {
        float rs = sden[dst];
        float4 o;
        float* op = &o.x;
#pragma unroll
        for (int j = 0; j < 4; j++) {
            float v = acc[j] * rs + bias[f0 + j];
            op[j] = (v > 0.f) ? v : 0.f;
        }
        *(float4*)&out2[(size_t)dst * 64 + f0] = o;
    }
}

// ---------------- fused mean-pool (sorted batch) + classifier --------
__global__ void k_pool_final(const float* __restrict__ out2, const int* __restrict__ batch,
                             const float* __restrict__ Wl, const float* __restrict__ bl,
                             float* __restrict__ out)
{
    int g = blockIdx.x;
    int lo, hi;
    { int a = 0, b = NN; while (a < b) { int mm = (a + b) >> 1; if (batch[mm] < g) a = mm + 1; else b = mm; } lo = a; }
    { int a = lo, b = NN; while (a < b) { int mm = (a + b) >> 1; if (batch[mm] < g + 1) a = mm + 1; else b = mm; } hi = a; }
    int t = threadIdx.x, c = t & 63, r = t >> 6;
    float s = 0.f;
    for (int n = lo + r; n < hi; n += 4) s += out2[(size_t)n * 64 + c];
    __shared__ float red[256];
    red[t] = s;
    __syncthreads();
    if (t < 64) {
        float p = red[t] + red[t + 64] + red[t + 128] + red[t + 192];
        int cntv = hi - lo;
        p /= (float)(cntv > 0 ? cntv : 1);
        float r0 = p * Wl[t * 2 + 0];
        float r1 = p * Wl[t * 2 + 1];
#pragma unroll
        for (int off = 32; off > 0; off >>= 1) {
            r0 += __shfl_xor(r0, off);
            r1 += __shfl_xor(r1, off);
        }
        if (t == 0) {
            out[g * 2 + 0] = r0 + bl[0];
            out[g * 2 + 1] = r1 + bl[1];
        }
    }
}

extern "C" void kernel_launch(void* const* d_in, const int* in_sizes, int n_in,
                              void* d_out, int out_size, void* d_ws, size_t ws_size,
                              hipStream_t stream)
{
    const float* x    = (const float*)d_in[0];
    const int*   ei   = (const int*)  d_in[1];
    const int*   batch= (const int*)  d_in[2];
    const float* W1   = (const float*)d_in[3];
    const float* as1  = (const float*)d_in[4];
    const float* ad1  = (const float*)d_in[5];
    const float* b1   = (const float*)d_in[6];
    const float* W2   = (const float*)d_in[7];
    const float* as2  = (const float*)d_in[8];
    const float* ad2  = (const float*)d_in[9];
    const float* b2   = (const float*)d_in[10];
    const float* Wl   = (const float*)d_in[11];
    const float* bl   = (const float*)d_in[12];
    float* out = (float*)d_out;

    // ---- workspace carve-up (int units) ----
    int* p = (int*)d_ws;
    int*   deg    = p;          p += 50048;
    int*   cursor = p;          p += 50048;
    int*   part   = p;          p += 256;
    int*   rowptr = p;          p += 50064;
    int*   csr    = p;          p += 850048;
    float* al1s   = (float*)p;  p += 200000;
    float* al1d   = (float*)p;  p += 200000;
    float* al2s   = (float*)p;  p += 50048;
    float* al2d   = (float*)p;  p += 50048;
    float* sden1  = (float*)p;  p += 200000;
    float* sden2  = (float*)p;  p += 50048;
    float* alphaE = (float*)p;  p += 4 * NETP;    // layer1 AoS [edge][4]; layer2 reuses [edge]
    ushort_t* Wt1 = (ushort_t*)p; p += 65536;     // 131072 ush
    ushort_t* Wt2 = (ushort_t*)p; p += 8192;      // 16384 ush
    ushort_t* h1b = (ushort_t*)p; p += 6400000;   // 50000*256 ush
    ushort_t* out1b = (ushort_t*)p; p += 6422528; // 50176*256 ush
    ushort_t* h2b = (ushort_t*)p; p += 1600000;   // 50000*64 ush
    float* out2   = (float*)h1b;                  // alias: h1b dead after gather1

    hipMemsetAsync(deg, 0, 2 * 50048 * sizeof(int), stream);               // deg+cursor
    hipMemsetAsync(out1b + (size_t)50000 * 256, 0,
                   (size_t)176 * 256 * sizeof(ushort_t), stream);          // GEMM2 M-pad

    // prep (deg histogram + weight casts) and CSR build
    k_prep      <<<3897, 256, 0, stream>>>(ei, deg, W1, Wt1, W2, Wt2);
    k_scan_part <<<196, 256, 0, stream>>>(deg, part);
    k_scan_top  <<<1,   256, 0, stream>>>(part, 196);
    k_scan_apply<<<196, 256, 0, stream>>>(deg, part, rowptr);
    k_fill      <<<(NET + 255) / 256, 256, 0, stream>>>(ei, rowptr, cursor, csr);

    // layer 1: GEMM (fp32 A staged->bf16) + logits; alpha pass; pure-FMA gather
    k_mfma<512, KIN, KIN, 128, 128, 2, 4, true><<<dim3(2, 391), 256, 0, stream>>>(
        x, Wt1, as1, ad1, h1b, al1s, al1d);
    k_alpha<4> <<<(NN + 3) / 4, 256, 0, stream>>>(rowptr, csr, al1s, al1d, alphaE, sden1);
    k_gather1  <<<(NN + 3) / 4, 256, 0, stream>>>(rowptr, csr, h1b, alphaE, sden1, b1, out1b);

    // layer 2: GEMM (bf16 A via global_load_lds) + logits; alpha pass; gather
    k_mfma<256, 256, 256, 256, 64, 4, 1, false><<<dim3(1, 196), 256, 0, stream>>>(
        out1b, Wt2, as2, ad2, h2b, al2s, al2d);
    k_alpha<1> <<<(NN + 3) / 4, 256, 0, stream>>>(rowptr, csr, al2s, al2d, alphaE, sden2);
    k_gather2  <<<(NN + 3) / 4, 256, 0, stream>>>(rowptr, csr, h2b, alphaE, sden2, b2, out2);

    // fused pool + classifier
    k_pool_final<<<NG, 256, 0, stream>>>(out2, batch, Wl, bl, out);
}

// Round 7
// 519.923 us; speedup vs baseline: 1.2094x; 1.0610x over previous
//
#include <hip/hip_runtime.h>
#include <math.h>

#define NN    50000
#define NE    800000
#define NET   850000     // edges + self loops
#define NETP  850048
#define NG    64
#define KIN   500
#define NEG   0.2f

typedef unsigned short ushort_t;
typedef __attribute__((ext_vector_type(8))) short bf8_t;       // 8 bf16 in 4 VGPRs
typedef __attribute__((ext_vector_type(8))) unsigned short us8_t;
typedef __attribute__((ext_vector_type(4))) float f4_t;

__device__ __forceinline__ float bf2f(ushort_t u) {
    unsigned v = ((unsigned)u) << 16;
    return __builtin_bit_cast(float, v);
}
__device__ __forceinline__ ushort_t f2bf(float f) {
    unsigned b = __builtin_bit_cast(unsigned, f);
    unsigned r = (b + 0x7FFFu + ((b >> 16) & 1u)) >> 16;   // RNE
    return (ushort_t)r;
}

#define GLOAD_LDS(g, l)                                                        \
    __builtin_amdgcn_global_load_lds(                                          \
        (const __attribute__((address_space(1))) unsigned int*)(g),            \
        (__attribute__((address_space(3))) unsigned int*)(l), 16, 0, 0)

// ---------------- prep: degree count + weight transpose/cast (merged) ----------
__global__ void k_prep(const int* __restrict__ ei, int* __restrict__ deg,
                       const float* __restrict__ W1, ushort_t* __restrict__ Wt1,
                       const float* __restrict__ W2, ushort_t* __restrict__ Wt2)
{
    int b = blockIdx.x;
    if (b < 3321) {                                  // degree histogram
        int e = b * 256 + threadIdx.x;
        if (e < NET) {
            int dst = (e < NE) ? ei[NE + e] : (e - NE);
            atomicAdd(&deg[dst], 1);
        }
    } else if (b < 3321 + 512) {                     // Wt1 [256][512] (K-pad 500->512)
        int idx = (b - 3321) * 256 + threadIdx.x;
        int n = idx >> 9, k = idx & 511;
        Wt1[idx] = f2bf(k < KIN ? W1[(size_t)k * 256 + n] : 0.f);
    } else {                                         // Wt2 [64][256]
        int idx = (b - 3833) * 256 + threadIdx.x;
        int n = idx >> 8, k = idx & 255;
        Wt2[idx] = f2bf(W2[(size_t)k * 64 + n]);
    }
}

// ---------------- CSR scan + fill ----------------
__global__ void k_scan_part(const int* __restrict__ deg, int* __restrict__ part) {
    __shared__ int s[256];
    int t = threadIdx.x;
    int i = blockIdx.x * 256 + t;
    s[t] = (i < NN) ? deg[i] : 0;
    __syncthreads();
    for (int off = 128; off > 0; off >>= 1) {
        if (t < off) s[t] += s[t + off];
        __syncthreads();
    }
    if (t == 0) part[blockIdx.x] = s[0];
}

__global__ void k_scan_top(int* __restrict__ part, int nb) {
    __shared__ int s[256];
    int t = threadIdx.x;
    int v = (t < nb) ? part[t] : 0;
    s[t] = v;
    __syncthreads();
    for (int off = 1; off < 256; off <<= 1) {
        int a = (t >= off) ? s[t - off] : 0;
        __syncthreads();
        s[t] += a;
        __syncthreads();
    }
    if (t < nb) part[t] = s[t] - v;   // exclusive
}

__global__ void k_scan_apply(const int* __restrict__ deg, const int* __restrict__ part,
                             int* __restrict__ rowptr) {
    __shared__ int s[256];
    int t = threadIdx.x;
    int i = blockIdx.x * 256 + t;
    int v = (i < NN) ? deg[i] : 0;
    s[t] = v;
    __syncthreads();
    for (int off = 1; off < 256; off <<= 1) {
        int a = (t >= off) ? s[t - off] : 0;
        __syncthreads();
        s[t] += a;
        __syncthreads();
    }
    if (i < NN) rowptr[i] = part[blockIdx.x] + s[t] - v;
    if (i == 0) rowptr[NN] = NET;
}

__global__ void k_fill(const int* __restrict__ ei, const int* __restrict__ rowptr,
                       int* __restrict__ cursor, int* __restrict__ csr) {
    int e = blockIdx.x * 256 + threadIdx.x;
    if (e >= NET) return;
    int src, dst;
    if (e < NE) { src = ei[e]; dst = ei[NE + e]; }
    else        { src = dst = e - NE; }
    int pos = atomicAdd(&cursor[dst], 1);
    csr[rowptr[dst] + pos] = src;
}

// ---------------- bf16 MFMA GEMM with register-prefetch A pipeline ----
// A-loads for step k+1 issue during step k's MFMA phase; consumed at the next
// LDS-write. AF32: fp32 A converted to bf16 at the LDS write (no cast pass).
template <int K, int KSRC, int LDA, int BM, int BN, int WM, int HEADS, bool AF32>
__global__ __launch_bounds__(256) void k_mfma(
    const void* __restrict__ Ap, const ushort_t* __restrict__ Wt,
    const float* __restrict__ a_s, const float* __restrict__ a_d,
    ushort_t* __restrict__ Hb, float* __restrict__ als, float* __restrict__ ald)
{
    __shared__ __align__(16) ushort_t lA[BM * 32];
    __shared__ __align__(16) ushort_t lB[BN * 32];
    const int FOUT = HEADS * 64;
    const int t    = threadIdx.x;
    const int row0 = blockIdx.y * BM;
    const int n0   = blockIdx.x * BN;
    const int ww   = t >> 6, lane = t & 63;
    const int wm   = ww % WM, wn = ww / WM;
    const int lrow = lane & 15, lq = lane >> 4;   // quad

    constexpr int NCH32 = BM * 32 / 1024;   // float4 chunks/thread (AF32)
    constexpr int NCH16 = BM * 32 / 2048;   // us8 chunks/thread (bf16)
    float4 pf32[AF32 ? NCH32 : 1];
    us8_t  pf16[AF32 ? 1 : NCH16];

    f4_t acc[4][4] = {};

    auto issueA = [&](int k0) {
        if constexpr (AF32) {
            const float* Af = (const float*)Ap;
#pragma unroll
            for (int i = 0; i < NCH32; i++) {
                int c = i * 256 + t;
                int row = c >> 3, kq = c & 7;
                int rg = row0 + row; if (rg >= NN) rg = 0;   // clamp pad rows
                int kg = k0 + kq * 4;
                pf32[i] = (kg < KSRC) ? *(const float4*)&Af[(size_t)rg * LDA + kg]
                                      : make_float4(0.f, 0.f, 0.f, 0.f);
            }
        } else {
            const ushort_t* Ab = (const ushort_t*)Ap;
#pragma unroll
            for (int i = 0; i < NCH16; i++) {
                int c = i * 256 + t;
                int row = c >> 2, kq = c & 3;
                pf16[i] = *(const us8_t*)&Ab[(size_t)(row0 + row) * LDA + k0 + kq * 8];
            }
        }
    };
    auto writeA = [&]() {
        if constexpr (AF32) {
#pragma unroll
            for (int i = 0; i < NCH32; i++) {
                int c = i * 256 + t;
                int row = c >> 3, kq = c & 7;
                *(ushort4*)&lA[row * 32 + kq * 4] = make_ushort4(
                    f2bf(pf32[i].x), f2bf(pf32[i].y), f2bf(pf32[i].z), f2bf(pf32[i].w));
            }
        } else {
#pragma unroll
            for (int i = 0; i < NCH16; i++) {
                int c = i * 256 + t;
                int row = c >> 2, kq = c & 3;
                *(us8_t*)&lA[row * 32 + kq * 8] = pf16[i];
            }
        }
    };

    issueA(0);
    for (int k0 = 0; k0 < K; k0 += 32) {
        writeA();                                  // drains pending A loads
#pragma unroll
        for (int i = 0; i < BN / 64; i++) {        // B tile via global_load_lds
            int c = i * 256 + t;
            int row = c >> 2, kq = c & 3;
            const ushort_t* gp = Wt + (size_t)(n0 + row) * K + k0 + kq * 8;
            GLOAD_LDS(gp, &lB[c * 8]);
        }
        __syncthreads();
        bf8_t af[4], bfr[4];
#pragma unroll
        for (int i = 0; i < 4; i++)
            af[i] = *(const bf8_t*)&lA[(wm * 64 + i * 16 + lrow) * 32 + lq * 8];
#pragma unroll
        for (int j = 0; j < 4; j++)
            bfr[j] = *(const bf8_t*)&lB[(wn * 64 + j * 16 + lrow) * 32 + lq * 8];
        if (k0 + 32 < K) issueA(k0 + 32);          // prefetch next tile (overlaps MFMA)
#pragma unroll
        for (int i = 0; i < 4; i++)
#pragma unroll
            for (int j = 0; j < 4; j++)
                acc[i][j] = __builtin_amdgcn_mfma_f32_16x16x32_bf16(af[i], bfr[j], acc[i][j], 0, 0, 0);
        __syncthreads();
    }

    // epilogue: wave's 64 cols = one head (64-aligned); contiguous H write + logits
    const int head = (n0 + wn * 64) >> 6;
    float as4[4], ad4[4];
#pragma unroll
    for (int j = 0; j < 4; j++) {
        as4[j] = a_s[head * 64 + j * 16 + lrow];
        ad4[j] = a_d[head * 64 + j * 16 + lrow];
    }
#pragma unroll
    for (int i = 0; i < 4; i++) {
#pragma unroll
        for (int r = 0; r < 4; r++) {
            int row = row0 + wm * 64 + i * 16 + lq * 4 + r;
            float v0 = acc[i][0][r], v1 = acc[i][1][r], v2 = acc[i][2][r], v3 = acc[i][3][r];
            if (row < NN) {
                size_t base = (size_t)row * FOUT + n0 + wn * 64 + lrow;
                Hb[base +  0] = f2bf(v0);
                Hb[base + 16] = f2bf(v1);
                Hb[base + 32] = f2bf(v2);
                Hb[base + 48] = f2bf(v3);
            }
            float ps = v0 * as4[0] + v1 * as4[1] + v2 * as4[2] + v3 * as4[3];
            float pd = v0 * ad4[0] + v1 * ad4[1] + v2 * ad4[2] + v3 * ad4[3];
#pragma unroll
            for (int off = 1; off < 16; off <<= 1) {
                ps += __shfl_xor(ps, off);
                pd += __shfl_xor(pd, off);
            }
            if (lrow == 0 && row < NN) {
                als[(size_t)row * HEADS + head] = ps;
                ald[(size_t)row * HEADS + head] = pd;
            }
        }
    }
}

// ---- softmax pass: exact per-(dst,head) max -> exp -> denom.
// alphaE stored AoS [edge][HEADS]. One wave per dst; lane = slot*HEADS + head.
template <int HEADS>
__global__ __launch_bounds__(256) void k_alpha(
    const int* __restrict__ rowptr, const int* __restrict__ csr,
    const float* __restrict__ als, const float* __restrict__ ald,
    float* __restrict__ alphaE, float* __restrict__ sden)
{
    const int SLOTS = 64 / HEADS;
    int w = threadIdx.x >> 6, lane = threadIdx.x & 63;
    int dst = blockIdx.x * 4 + w;
    if (dst >= NN) return;
    const int slot = lane / HEADS, head = lane & (HEADS - 1);
    const int beg = rowptr[dst], end = rowptr[dst + 1];
    const float adst = ald[dst * HEADS + head];

    float m = -1e30f;
    for (int i = beg + slot; i < end; i += SLOTS) {
        float e = als[csr[i] * HEADS + head] + adst;
        e = (e > 0.f) ? e : NEG * e;
        m = fmaxf(m, e);
    }
#pragma unroll
    for (int off = HEADS; off < 64; off <<= 1) m = fmaxf(m, __shfl_xor(m, off));

    float s = 0.f;
    for (int i = beg + slot; i < end; i += SLOTS) {
        float e = als[csr[i] * HEADS + head] + adst;
        e = (e > 0.f) ? e : NEG * e;
        float ex = __expf(e - m);
        s += ex;
        alphaE[(size_t)i * HEADS + head] = ex;
    }
#pragma unroll
    for (int off = HEADS; off < 64; off <<= 1) s += __shfl_xor(s, off);
    if (slot == 0) sden[dst * HEADS + head] = 1.f / (s + 1e-16f);
}

// ---- layer-1 gather: one wave per dst, all 4 heads, 2 full rows/iter, pure FMA ----
__global__ __launch_bounds__(256) void k_gather1(
    const int* __restrict__ rowptr, const int* __restrict__ csr,
    const ushort_t* __restrict__ Hb, const float* __restrict__ alphaE,
    const float* __restrict__ sden, const float* __restrict__ bias,
    ushort_t* __restrict__ out1b)
{
    int w = threadIdx.x >> 6, lane = threadIdx.x & 63;
    int dst = blockIdx.x * 4 + w;
    if (dst >= NN) return;
    const int slot = lane >> 5;
    const int head = (lane >> 3) & 3;
    const int f0   = (lane & 7) * 8;
    const int beg = rowptr[dst], end = rowptr[dst + 1];

    float acc[8] = {};
    for (int i = beg + slot; i < end; i += 2) {
        int   src = csr[i];
        float a   = alphaE[(size_t)i * 4 + head];
        us8_t x8  = *(const us8_t*)&Hb[(size_t)src * 256 + head * 64 + f0];
#pragma unroll
        for (int j = 0; j < 8; j++)
            acc[j] += a * bf2f((ushort_t)x8[j]);
    }
#pragma unroll
    for (int j = 0; j < 8; j++) acc[j] += __shfl_xor(acc[j], 32);
    if (lane < 32) {
        float rs = sden[dst * 4 + head];
        us8_t o8;
#pragma unroll
        for (int j = 0; j < 8; j++) {
            float o = acc[j] * rs + bias[head * 64 + f0 + j];
            o8[j] = f2bf((o > 0.f) ? o : 0.f);
        }
        *(us8_t*)&out1b[(size_t)dst * 256 + head * 64 + f0] = o8;
    }
}

// ---- layer-2 gather: one wave per dst, 4 rows/iter, pure FMA ----
__global__ __launch_bounds__(256) void k_gather2(
    const int* __restrict__ rowptr, const int* __restrict__ csr,
    const ushort_t* __restrict__ Hb, const float* __restrict__ alphaE,
    const float* __restrict__ sden, const float* __restrict__ bias,
    float* __restrict__ out2)
{
    int w = threadIdx.x >> 6, lane = threadIdx.x & 63;
    int dst = blockIdx.x * 4 + w;
    if (dst >= NN) return;
    const int slot = lane >> 4;
    const int f0   = (lane & 15) * 4;
    const int beg = rowptr[dst], end = rowptr[dst + 1];

    float acc[4] = {};
    for (int i = beg + slot; i < end; i += 4) {
        int src = csr[i];
        float a = alphaE[i];
        ushort4 xv = *(const ushort4*)&Hb[(size_t)src * 64 + f0];
        acc[0] += a * bf2f(xv.x);
        acc[1] += a * bf2f(xv.y);
        acc[2] += a * bf2f(xv.z);
        acc[3] += a * bf2f(xv.w);
    }
#pragma unroll
    for (int j = 0; j < 4; j++) {
        acc[j] += __shfl_xor(acc[j], 16);
        acc[j] += __shfl_xor(acc[j], 32);
    }
    if (lane < 16) {
        float rs = sden[dst];
        float4 o;
        float* op = &o.x;
#pragma unroll
        for (int j = 0; j < 4; j++) {
            float v = acc[j] * rs + bias[f0 + j];
            op[j] = (v > 0.f) ? v : 0.f;
        }
        *(float4*)&out2[(size_t)dst * 64 + f0] = o;
    }
}

// ---------------- fused mean-pool (sorted batch) + classifier --------
__global__ void k_pool_final(const float* __restrict__ out2, const int* __restrict__ batch,
                             const float* __restrict__ Wl, const float* __restrict__ bl,
                             float* __restrict__ out)
{
    int g = blockIdx.x;
    int lo, hi;
    { int a = 0, b = NN; while (a < b) { int mm = (a + b) >> 1; if (batch[mm] < g) a = mm + 1; else b = mm; } lo = a; }
    { int a = lo, b = NN; while (a < b) { int mm = (a + b) >> 1; if (batch[mm] < g + 1) a = mm + 1; else b = mm; } hi = a; }
    int t = threadIdx.x, c = t & 63, r = t >> 6;
    float s = 0.f;
    for (int n = lo + r; n < hi; n += 4) s += out2[(size_t)n * 64 + c];
    __shared__ float red[256];
    red[t] = s;
    __syncthreads();
    if (t < 64) {
        float p = red[t] + red[t + 64] + red[t + 128] + red[t + 192];
        int cntv = hi - lo;
        p /= (float)(cntv > 0 ? cntv : 1);
        float r0 = p * Wl[t * 2 + 0];
        float r1 = p * Wl[t * 2 + 1];
#pragma unroll
        for (int off = 32; off > 0; off >>= 1) {
            r0 += __shfl_xor(r0, off);
            r1 += __shfl_xor(r1, off);
        }
        if (t == 0) {
            out[g * 2 + 0] = r0 + bl[0];
            out[g * 2 + 1] = r1 + bl[1];
        }
    }
}

extern "C" void kernel_launch(void* const* d_in, const int* in_sizes, int n_in,
                              void* d_out, int out_size, void* d_ws, size_t ws_size,
                              hipStream_t stream)
{
    const float* x    = (const float*)d_in[0];
    const int*   ei   = (const int*)  d_in[1];
    const int*   batch= (const int*)  d_in[2];
    const float* W1   = (const float*)d_in[3];
    const float* as1  = (const float*)d_in[4];
    const float* ad1  = (const float*)d_in[5];
    const float* b1   = (const float*)d_in[6];
    const float* W2   = (const float*)d_in[7];
    const float* as2  = (const float*)d_in[8];
    const float* ad2  = (const float*)d_in[9];
    const float* b2   = (const float*)d_in[10];
    const float* Wl   = (const float*)d_in[11];
    const float* bl   = (const float*)d_in[12];
    float* out = (float*)d_out;

    // ---- workspace carve-up (int units) ----
    int* p = (int*)d_ws;
    int*   deg    = p;          p += 50048;
    int*   cursor = p;          p += 50048;
    int*   part   = p;          p += 256;
    int*   rowptr = p;          p += 50064;
    int*   csr    = p;          p += 850048;
    float* al1s   = (float*)p;  p += 200000;
    float* al1d   = (float*)p;  p += 200000;
    float* al2s   = (float*)p;  p += 50048;
    float* al2d   = (float*)p;  p += 50048;
    float* sden1  = (float*)p;  p += 200000;
    float* sden2  = (float*)p;  p += 50048;
    float* alphaE = (float*)p;  p += 4 * NETP;    // layer1 AoS [edge][4]; layer2 reuses [edge]
    ushort_t* Wt1 = (ushort_t*)p; p += 65536;     // 131072 ush
    ushort_t* Wt2 = (ushort_t*)p; p += 8192;      // 16384 ush
    ushort_t* h1b = (ushort_t*)p; p += 6400000;   // 50000*256 ush
    ushort_t* out1b = (ushort_t*)p; p += 6422528; // 50176*256 ush
    ushort_t* h2b = (ushort_t*)p; p += 1600000;   // 50000*64 ush
    float* out2   = (float*)h1b;                  // alias: h1b dead after gather1

    hipMemsetAsync(deg, 0, 2 * 50048 * sizeof(int), stream);               // deg+cursor
    hipMemsetAsync(out1b + (size_t)50000 * 256, 0,
                   (size_t)176 * 256 * sizeof(ushort_t), stream);          // GEMM2 M-pad

    // prep (deg histogram + weight casts) and CSR build
    k_prep      <<<3897, 256, 0, stream>>>(ei, deg, W1, Wt1, W2, Wt2);
    k_scan_part <<<196, 256, 0, stream>>>(deg, part);
    k_scan_top  <<<1,   256, 0, stream>>>(part, 196);
    k_scan_apply<<<196, 256, 0, stream>>>(deg, part, rowptr);
    k_fill      <<<(NET + 255) / 256, 256, 0, stream>>>(ei, rowptr, cursor, csr);

    // layer 1: GEMM (fp32 A, register-prefetch pipeline) + logits; alpha; gather
    k_mfma<512, KIN, KIN, 128, 128, 2, 4, true><<<dim3(2, 391), 256, 0, stream>>>(
        x, Wt1, as1, ad1, h1b, al1s, al1d);
    k_alpha<4> <<<(NN + 3) / 4, 256, 0, stream>>>(rowptr, csr, al1s, al1d, alphaE, sden1);
    k_gather1  <<<(NN + 3) / 4, 256, 0, stream>>>(rowptr, csr, h1b, alphaE, sden1, b1, out1b);

    // layer 2: GEMM (bf16 A, register-prefetch pipeline) + logits; alpha; gather
    k_mfma<256, 256, 256, 256, 64, 4, 1, false><<<dim3(1, 196), 256, 0, stream>>>(
        out1b, Wt2, as2, ad2, h2b, al2s, al2d);
    k_alpha<1> <<<(NN + 3) / 4, 256, 0, stream>>>(rowptr, csr, al2s, al2d, alphaE, sden2);
    k_gather2  <<<(NN + 3) / 4, 256, 0, stream>>>(rowptr, csr, h2b, alphaE, sden2, b2, out2);

    // fused pool + classifier
    k_pool_final<<<NG, 256, 0, stream>>>(out2, batch, Wl, bl, out);
}

// Round 8
// 517.126 us; speedup vs baseline: 1.2159x; 1.0054x over previous
//
#include <hip/hip_runtime.h>
#include <math.h>

#define NN    50000
#define NE    800000
#define NET   850000     // edges + self loops
#define NETP  850048
#define NG    64
#define KIN   500
#define NEG   0.2f

typedef unsigned short ushort_t;
typedef __attribute__((ext_vector_type(8))) short bf8_t;       // 8 bf16 in 4 VGPRs
typedef __attribute__((ext_vector_type(8))) unsigned short us8_t;
typedef __attribute__((ext_vector_type(4))) float f4_t;

__device__ __forceinline__ float bf2f(ushort_t u) {
    unsigned v = ((unsigned)u) << 16;
    return __builtin_bit_cast(float, v);
}
__device__ __forceinline__ ushort_t f2bf(float f) {
    unsigned b = __builtin_bit_cast(unsigned, f);
    unsigned r = (b + 0x7FFFu + ((b >> 16) & 1u)) >> 16;   // RNE
    return (ushort_t)r;
}

#define GLOAD_LDS(g, l)                                                        \
    __builtin_amdgcn_global_load_lds(                                          \
        (const __attribute__((address_space(1))) unsigned int*)(g),            \
        (__attribute__((address_space(3))) unsigned int*)(l), 16, 0, 0)

// ---------------- prep: degree count + weight transpose/cast (merged) ----------
__global__ void k_prep(const int* __restrict__ ei, int* __restrict__ deg,
                       const float* __restrict__ W1, ushort_t* __restrict__ Wt1,
                       const float* __restrict__ W2, ushort_t* __restrict__ Wt2)
{
    int b = blockIdx.x;
    if (b < 3321) {                                  // degree histogram
        int e = b * 256 + threadIdx.x;
        if (e < NET) {
            int dst = (e < NE) ? ei[NE + e] : (e - NE);
            atomicAdd(&deg[dst], 1);
        }
    } else if (b < 3321 + 512) {                     // Wt1 [256][512] (K-pad 500->512)
        int idx = (b - 3321) * 256 + threadIdx.x;
        int n = idx >> 9, k = idx & 511;
        Wt1[idx] = f2bf(k < KIN ? W1[(size_t)k * 256 + n] : 0.f);
    } else {                                         // Wt2 [64][256]
        int idx = (b - 3833) * 256 + threadIdx.x;
        int n = idx >> 8, k = idx & 255;
        Wt2[idx] = f2bf(W2[(size_t)k * 64 + n]);
    }
}

// ---------------- CSR scan + fill ----------------
__global__ void k_scan_part(const int* __restrict__ deg, int* __restrict__ part) {
    __shared__ int s[256];
    int t = threadIdx.x;
    int i = blockIdx.x * 256 + t;
    s[t] = (i < NN) ? deg[i] : 0;
    __syncthreads();
    for (int off = 128; off > 0; off >>= 1) {
        if (t < off) s[t] += s[t + off];
        __syncthreads();
    }
    if (t == 0) part[blockIdx.x] = s[0];
}

__global__ void k_scan_top(int* __restrict__ part, int nb) {
    __shared__ int s[256];
    int t = threadIdx.x;
    int v = (t < nb) ? part[t] : 0;
    s[t] = v;
    __syncthreads();
    for (int off = 1; off < 256; off <<= 1) {
        int a = (t >= off) ? s[t - off] : 0;
        __syncthreads();
        s[t] += a;
        __syncthreads();
    }
    if (t < nb) part[t] = s[t] - v;   // exclusive
}

__global__ void k_scan_apply(const int* __restrict__ deg, const int* __restrict__ part,
                             int* __restrict__ rowptr) {
    __shared__ int s[256];
    int t = threadIdx.x;
    int i = blockIdx.x * 256 + t;
    int v = (i < NN) ? deg[i] : 0;
    s[t] = v;
    __syncthreads();
    for (int off = 1; off < 256; off <<= 1) {
        int a = (t >= off) ? s[t - off] : 0;
        __syncthreads();
        s[t] += a;
        __syncthreads();
    }
    if (i < NN) rowptr[i] = part[blockIdx.x] + s[t] - v;
    if (i == 0) rowptr[NN] = NET;
}

__global__ void k_fill(const int* __restrict__ ei, const int* __restrict__ rowptr,
                       int* __restrict__ cursor, int* __restrict__ csr) {
    int e = blockIdx.x * 256 + threadIdx.x;
    if (e >= NET) return;
    int src, dst;
    if (e < NE) { src = ei[e]; dst = ei[NE + e]; }
    else        { src = dst = e - NE; }
    int pos = atomicAdd(&cursor[dst], 1);
    csr[rowptr[dst] + pos] = src;
}

// ---------------- bf16 MFMA GEMM ----
// Block: 256 threads = 4 waves as WM x WN grid; wave tile (BM/WM) x 64.
// AF32: fp32 A register-prefetch pipeline (load k+1 during MFMA of k),
//       converted to bf16 at the LDS write. !AF32: m97-style global_load_lds.
template <int K, int KSRC, int LDA, int BM, int BN, int WM, int WN, int HEADS, bool AF32>
__global__ __launch_bounds__(256) void k_mfma(
    const void* __restrict__ Ap, const ushort_t* __restrict__ Wt,
    const float* __restrict__ a_s, const float* __restrict__ a_d,
    ushort_t* __restrict__ Hb, float* __restrict__ als, float* __restrict__ ald)
{
    __shared__ __align__(16) ushort_t lA[BM * 32];
    __shared__ __align__(16) ushort_t lB[BN * 32];
    const int FOUT = HEADS * 64;
    const int t    = threadIdx.x;
    const int row0 = blockIdx.y * BM;
    const int n0   = blockIdx.x * BN;
    const int ww   = t >> 6, lane = t & 63;
    const int wm   = ww % WM, wn = ww / WM;
    const int lrow = lane & 15, lq = lane >> 4;   // quad
    constexpr int RS = BM / WM;    // rows per wave
    constexpr int RF = RS / 16;    // row fragments per wave
    constexpr int NCH32 = BM / 32; // float4 chunks/thread (AF32 staging)

    float4 pf32[AF32 ? NCH32 : 1];
    f4_t acc[RF][4] = {};

    auto issueA = [&](int k0) {
        const float* Af = (const float*)Ap;
#pragma unroll
        for (int i = 0; i < NCH32; i++) {
            int c = i * 256 + t;
            int row = c >> 3, kq = c & 7;
            int rg = row0 + row; if (rg >= NN) rg = 0;   // clamp pad rows
            int kg = k0 + kq * 4;
            pf32[i] = (kg < KSRC) ? *(const float4*)&Af[(size_t)rg * LDA + kg]
                                  : make_float4(0.f, 0.f, 0.f, 0.f);
        }
    };
    auto writeA = [&]() {
#pragma unroll
        for (int i = 0; i < NCH32; i++) {
            int c = i * 256 + t;
            int row = c >> 3, kq = c & 7;
            *(ushort4*)&lA[row * 32 + kq * 4] = make_ushort4(
                f2bf(pf32[i].x), f2bf(pf32[i].y), f2bf(pf32[i].z), f2bf(pf32[i].w));
        }
    };
    auto stageB = [&](int k0) {
#pragma unroll
        for (int i = 0; i < BN / 64; i++) {
            int c = i * 256 + t;
            int row = c >> 2, kq = c & 3;
            const ushort_t* gp = Wt + (size_t)(n0 + row) * K + k0 + kq * 8;
            GLOAD_LDS(gp, &lB[c * 8]);
        }
    };

    if constexpr (AF32) issueA(0);
    for (int k0 = 0; k0 < K; k0 += 32) {
        if constexpr (AF32) {
            writeA();                              // drains pending A loads
        } else {
            const ushort_t* Ab = (const ushort_t*)Ap;
#pragma unroll
            for (int i = 0; i < BM / 64; i++) {    // A via global_load_lds (bf16)
                int c = i * 256 + t;
                int row = c >> 2, kq = c & 3;
                const ushort_t* gp = Ab + (size_t)(row0 + row) * LDA + k0 + kq * 8;
                GLOAD_LDS(gp, &lA[c * 8]);
            }
        }
        stageB(k0);
        __syncthreads();
        bf8_t af[RF], bfr[4];
#pragma unroll
        for (int i = 0; i < RF; i++)
            af[i] = *(const bf8_t*)&lA[(wm * RS + i * 16 + lrow) * 32 + lq * 8];
#pragma unroll
        for (int j = 0; j < 4; j++)
            bfr[j] = *(const bf8_t*)&lB[(wn * 64 + j * 16 + lrow) * 32 + lq * 8];
        if constexpr (AF32) { if (k0 + 32 < K) issueA(k0 + 32); }   // overlaps MFMA
#pragma unroll
        for (int i = 0; i < RF; i++)
#pragma unroll
            for (int j = 0; j < 4; j++)
                acc[i][j] = __builtin_amdgcn_mfma_f32_16x16x32_bf16(af[i], bfr[j], acc[i][j], 0, 0, 0);
        __syncthreads();
    }

    // epilogue: wave's 64 cols = one head (64-aligned); contiguous H write + logits
    const int head = (n0 + wn * 64) >> 6;
    float as4[4], ad4[4];
#pragma unroll
    for (int j = 0; j < 4; j++) {
        as4[j] = a_s[head * 64 + j * 16 + lrow];
        ad4[j] = a_d[head * 64 + j * 16 + lrow];
    }
#pragma unroll
    for (int i = 0; i < RF; i++) {
#pragma unroll
        for (int r = 0; r < 4; r++) {
            int row = row0 + wm * RS + i * 16 + lq * 4 + r;
            float v0 = acc[i][0][r], v1 = acc[i][1][r], v2 = acc[i][2][r], v3 = acc[i][3][r];
            if (row < NN) {
                size_t base = (size_t)row * FOUT + n0 + wn * 64 + lrow;
                Hb[base +  0] = f2bf(v0);
                Hb[base + 16] = f2bf(v1);
                Hb[base + 32] = f2bf(v2);
                Hb[base + 48] = f2bf(v3);
            }
            float ps = v0 * as4[0] + v1 * as4[1] + v2 * as4[2] + v3 * as4[3];
            float pd = v0 * ad4[0] + v1 * ad4[1] + v2 * ad4[2] + v3 * ad4[3];
#pragma unroll
            for (int off = 1; off < 16; off <<= 1) {
                ps += __shfl_xor(ps, off);
                pd += __shfl_xor(pd, off);
            }
            if (lrow == 0 && row < NN) {
                als[(size_t)row * HEADS + head] = ps;
                ald[(size_t)row * HEADS + head] = pd;
            }
        }
    }
}

// ---- softmax pass: exact per-(dst,head) max -> exp -> denom.
// alphaE stored AoS [edge][HEADS]. One wave per dst; lane = slot*HEADS + head.
template <int HEADS>
__global__ __launch_bounds__(256) void k_alpha(
    const int* __restrict__ rowptr, const int* __restrict__ csr,
    const float* __restrict__ als, const float* __restrict__ ald,
    float* __restrict__ alphaE, float* __restrict__ sden)
{
    const int SLOTS = 64 / HEADS;
    int w = threadIdx.x >> 6, lane = threadIdx.x & 63;
    int dst = blockIdx.x * 4 + w;
    if (dst >= NN) return;
    const int slot = lane / HEADS, head = lane & (HEADS - 1);
    const int beg = rowptr[dst], end = rowptr[dst + 1];
    const float adst = ald[dst * HEADS + head];

    float m = -1e30f;
    for (int i = beg + slot; i < end; i += SLOTS) {
        float e = als[csr[i] * HEADS + head] + adst;
        e = (e > 0.f) ? e : NEG * e;
        m = fmaxf(m, e);
    }
#pragma unroll
    for (int off = HEADS; off < 64; off <<= 1) m = fmaxf(m, __shfl_xor(m, off));

    float s = 0.f;
    for (int i = beg + slot; i < end; i += SLOTS) {
        float e = als[csr[i] * HEADS + head] + adst;
        e = (e > 0.f) ? e : NEG * e;
        float ex = __expf(e - m);
        s += ex;
        alphaE[(size_t)i * HEADS + head] = ex;
    }
#pragma unroll
    for (int off = HEADS; off < 64; off <<= 1) s += __shfl_xor(s, off);
    if (slot == 0) sden[dst * HEADS + head] = 1.f / (s + 1e-16f);
}

// ---- layer-1 gather: one wave per dst, all 4 heads, 2 full rows/iter, pure FMA ----
__global__ __launch_bounds__(256) void k_gather1(
    const int* __restrict__ rowptr, const int* __restrict__ csr,
    const ushort_t* __restrict__ Hb, const float* __restrict__ alphaE,
    const float* __restrict__ sden, const float* __restrict__ bias,
    ushort_t* __restrict__ out1b)
{
    int w = threadIdx.x >> 6, lane = threadIdx.x & 63;
    int dst = blockIdx.x * 4 + w;
    if (dst >= NN) return;
    const int slot = lane >> 5;
    const int head = (lane >> 3) & 3;
    const int f0   = (lane & 7) * 8;
    const int beg = rowptr[dst], end = rowptr[dst + 1];

    float acc[8] = {};
    for (int i = beg + slot; i < end; i += 2) {
        int   src = csr[i];
        float a   = alphaE[(size_t)i * 4 + head];
        us8_t x8  = *(const us8_t*)&Hb[(size_t)src * 256 + head * 64 + f0];
#pragma unroll
        for (int j = 0; j < 8; j++)
            acc[j] += a * bf2f((ushort_t)x8[j]);
    }
#pragma unroll
    for (int j = 0; j < 8; j++) acc[j] += __shfl_xor(acc[j], 32);
    if (lane < 32) {
        float rs = sden[dst * 4 + head];
        us8_t o8;
#pragma unroll
        for (int j = 0; j < 8; j++) {
            float o = acc[j] * rs + bias[head * 64 + f0 + j];
            o8[j] = f2bf((o > 0.f) ? o : 0.f);
        }
        *(us8_t*)&out1b[(size_t)dst * 256 + head * 64 + f0] = o8;
    }
}

// ---- layer-2 gather: one wave per dst, 4 rows/iter, pure FMA ----
__global__ __launch_bounds__(256) void k_gather2(
    const int* __restrict__ rowptr, const int* __restrict__ csr,
    const ushort_t* __restrict__ Hb, const float* __restrict__ alphaE,
    const float* __restrict__ sden, const float* __restrict__ bias,
    float* __restrict__ out2)
{
    int w = threadIdx.x >> 6, lane = threadIdx.x & 63;
    int dst = blockIdx.x * 4 + w;
    if (dst >= NN) return;
    const int slot = lane >> 4;
    const int f0   = (lane & 15) * 4;
    const int beg = rowptr[dst], end = rowptr[dst + 1];

    float acc[4] = {};
    for (int i = beg + slot; i < end; i += 4) {
        int src = csr[i];
        float a = alphaE[i];
        ushort4 xv = *(const ushort4*)&Hb[(size_t)src * 64 + f0];
        acc[0] += a * bf2f(xv.x);
        acc[1] += a * bf2f(xv.y);
        acc[2] += a * bf2f(xv.z);
        acc[3] += a * bf2f(xv.w);
    }
#pragma unroll
    for (int j = 0; j < 4; j++) {
        acc[j] += __shfl_xor(acc[j], 16);
        acc[j] += __shfl_xor(acc[j], 32);
    }
    if (lane < 16) {
        float rs = sden[dst];
        float4 o;
        float* op = &o.x;
#pragma unroll
        for (int j = 0; j < 4; j++) {
            float v = acc[j] * rs + bias[f0 + j];
            op[j] = (v > 0.f) ? v : 0.f;
        }
        *(float4*)&out2[(size_t)dst * 64 + f0] = o;
    }
}

// ---------------- fused mean-pool (sorted batch) + classifier --------
__global__ void k_pool_final(const float* __restrict__ out2, const int* __restrict__ batch,
                             const float* __restrict__ Wl, const float* __restrict__ bl,
                             float* __restrict__ out)
{
    int g = blockIdx.x;
    int lo, hi;
    { int a = 0, b = NN; while (a < b) { int mm = (a + b) >> 1; if (batch[mm] < g) a = mm + 1; else b = mm; } lo = a; }
    { int a = lo, b = NN; while (a < b) { int mm = (a + b) >> 1; if (batch[mm] < g + 1) a = mm + 1; else b = mm; } hi = a; }
    int t = threadIdx.x, c = t & 63, r = t >> 6;
    float s = 0.f;
    for (int n = lo + r; n < hi; n += 4) s += out2[(size_t)n * 64 + c];
    __shared__ float red[256];
    red[t] = s;
    __syncthreads();
    if (t < 64) {
        float p = red[t] + red[t + 64] + red[t + 128] + red[t + 192];
        int cntv = hi - lo;
        p /= (float)(cntv > 0 ? cntv : 1);
        float r0 = p * Wl[t * 2 + 0];
        float r1 = p * Wl[t * 2 + 1];
#pragma unroll
        for (int off = 32; off > 0; off >>= 1) {
            r0 += __shfl_xor(r0, off);
            r1 += __shfl_xor(r1, off);
        }
        if (t == 0) {
            out[g * 2 + 0] = r0 + bl[0];
            out[g * 2 + 1] = r1 + bl[1];
        }
    }
}

extern "C" void kernel_launch(void* const* d_in, const int* in_sizes, int n_in,
                              void* d_out, int out_size, void* d_ws, size_t ws_size,
                              hipStream_t stream)
{
    const float* x    = (const float*)d_in[0];
    const int*   ei   = (const int*)  d_in[1];
    const int*   batch= (const int*)  d_in[2];
    const float* W1   = (const float*)d_in[3];
    const float* as1  = (const float*)d_in[4];
    const float* ad1  = (const float*)d_in[5];
    const float* b1   = (const float*)d_in[6];
    const float* W2   = (const float*)d_in[7];
    const float* as2  = (const float*)d_in[8];
    const float* ad2  = (const float*)d_in[9];
    const float* b2   = (const float*)d_in[10];
    const float* Wl   = (const float*)d_in[11];
    const float* bl   = (const float*)d_in[12];
    float* out = (float*)d_out;

    // ---- workspace carve-up (int units) ----
    int* p = (int*)d_ws;
    int*   deg    = p;          p += 50048;
    int*   cursor = p;          p += 50048;
    int*   part   = p;          p += 256;
    int*   rowptr = p;          p += 50064;
    int*   csr    = p;          p += 850048;
    float* al1s   = (float*)p;  p += 200000;
    float* al1d   = (float*)p;  p += 200000;
    float* al2s   = (float*)p;  p += 50048;
    float* al2d   = (float*)p;  p += 50048;
    float* sden1  = (float*)p;  p += 200000;
    float* sden2  = (float*)p;  p += 50048;
    float* alphaE = (float*)p;  p += 4 * NETP;    // layer1 AoS [edge][4]; layer2 reuses [edge]
    ushort_t* Wt1 = (ushort_t*)p; p += 65536;     // 131072 ush
    ushort_t* Wt2 = (ushort_t*)p; p += 8192;      // 16384 ush
    ushort_t* h1b = (ushort_t*)p; p += 6400000;   // 50000*256 ush
    ushort_t* out1b = (ushort_t*)p; p += 6422528; // 50176*256 ush
    ushort_t* h2b = (ushort_t*)p; p += 1600000;   // 50000*64 ush
    float* out2   = (float*)h1b;                  // alias: h1b dead after gather1

    hipMemsetAsync(deg, 0, 2 * 50048 * sizeof(int), stream);               // deg+cursor
    hipMemsetAsync(out1b + (size_t)50000 * 256, 0,
                   (size_t)176 * 256 * sizeof(ushort_t), stream);          // GEMM2 M-pad

    // prep (deg histogram + weight casts) and CSR build
    k_prep      <<<3897, 256, 0, stream>>>(ei, deg, W1, Wt1, W2, Wt2);
    k_scan_part <<<196, 256, 0, stream>>>(deg, part);
    k_scan_top  <<<1,   256, 0, stream>>>(part, 196);
    k_scan_apply<<<196, 256, 0, stream>>>(deg, part, rowptr);
    k_fill      <<<(NET + 255) / 256, 256, 0, stream>>>(ei, rowptr, cursor, csr);

    // layer 1: GEMM BM=64 (1564 blocks, 6/CU) fp32-A register-prefetch; alpha; gather
    k_mfma<512, KIN, KIN, 64, 128, 2, 2, 4, true><<<dim3(2, 782), 256, 0, stream>>>(
        x, Wt1, as1, ad1, h1b, al1s, al1d);
    k_alpha<4> <<<(NN + 3) / 4, 256, 0, stream>>>(rowptr, csr, al1s, al1d, alphaE, sden1);
    k_gather1  <<<(NN + 3) / 4, 256, 0, stream>>>(rowptr, csr, h1b, alphaE, sden1, b1, out1b);

    // layer 2: GEMM BM=64 (782 blocks) bf16-A global_load_lds; alpha; gather
    k_mfma<256, 256, 256, 64, 64, 4, 1, 1, false><<<dim3(1, 782), 256, 0, stream>>>(
        out1b, Wt2, as2, ad2, h2b, al2s, al2d);
    k_alpha<1> <<<(NN + 3) / 4, 256, 0, stream>>>(rowptr, csr, al2s, al2d, alphaE, sden2);
    k_gather2  <<<(NN + 3) / 4, 256, 0, stream>>>(rowptr, csr, h2b, alphaE, sden2, b2, out2);

    // fused pool + classifier
    k_pool_final<<<NG, 256, 0, stream>>>(out2, batch, Wl, bl, out);
}